// Round 1
// baseline (62.571 us; speedup 1.0000x reference)
//
#include <hip/hip_runtime.h>

#define Bn 8
#define Nn 2048
#define Dn 128
#define OUTn 128

typedef __attribute__((ext_vector_type(8))) short bf16x8;     // MFMA A/B operand (8 bf16)
typedef __attribute__((ext_vector_type(8))) unsigned short ushort8;
typedef __attribute__((ext_vector_type(4))) float f32x4;      // MFMA C/D
typedef __attribute__((ext_vector_type(4))) int int4v;
typedef __attribute__((ext_vector_type(4))) float float4v;

__device__ __forceinline__ unsigned short f2bf(float f) {
  unsigned int u = __builtin_bit_cast(unsigned int, f);
  u += 0x7FFFu + ((u >> 16) & 1u);   // round-to-nearest-even
  return (unsigned short)(u >> 16);
}

// ---------------- prep 1: input [b][n][d] fp32 -> inputT [b][d][n] bf16 ----------------
__global__ __launch_bounds__(256) void gcn_transpose_in(const float* __restrict__ in,
                                                        unsigned short* __restrict__ inT) {
  const int b = blockIdx.x >> 5;
  const int n0 = (blockIdx.x & 31) * 64;
  __shared__ __attribute__((aligned(16))) unsigned short lds[64][130];
  const int tid = threadIdx.x;
  #pragma unroll
  for (int c = 0; c < 32; ++c) {
    int e = tid + c * 256;            // 0..8191
    int i = e >> 7, d = e & 127;
    lds[i][d] = f2bf(in[((size_t)(b * Nn + n0 + i)) * Dn + d]);
  }
  __syncthreads();
  #pragma unroll
  for (int c = 0; c < 4; ++c) {
    int ch = tid + c * 256;           // 0..1023
    int d = ch >> 3, g = (ch & 7) * 8;
    ushort8 v;
    #pragma unroll
    for (int e = 0; e < 8; ++e) v[e] = lds[g + e][d];
    *(ushort8*)(inT + ((size_t)(b * Dn + d)) * Nn + n0 + g) = v;
  }
}

// ---------------- prep 2: W [2D][OUT] fp32 -> WT [OUT][2D] bf16 ----------------
__global__ __launch_bounds__(256) void gcn_prep_wt(const float* __restrict__ W,
                                                   unsigned short* __restrict__ WT) {
  int gid = blockIdx.x * 256 + threadIdx.x;      // 0..32767
  int j = gid >> 8, k = gid & 255;               // WT[j][k] = W[k][j]
  WT[gid] = f2bf(W[k * OUTn + j]);
}

// ---------------- main fused kernel ----------------
// block: 256 threads (4 waves), handles rows [row0, row0+32) of batch bb.
__global__ __launch_bounds__(256) void gcn_main(
    const float* __restrict__ input_, const int* __restrict__ adj,
    const float* __restrict__ bvec, const unsigned short* __restrict__ inT,
    const unsigned short* __restrict__ WT, float* __restrict__ out) {
  constexpr int BM = 32, KB = 128, PAD = 8;
  __shared__ __attribute__((aligned(16))) unsigned short As[BM][KB + PAD];     //  8.7 KB
  __shared__ __attribute__((aligned(16))) unsigned short Bs[Dn][KB + PAD];     // 34.8 KB
  __shared__ __attribute__((aligned(16))) unsigned short feat[BM][2 * Dn + PAD]; // 16.9 KB
  __shared__ float degs[BM];
  __shared__ float rowsum[BM][4];

  const int tid = threadIdx.x;
  const int w = tid >> 6;          // wave 0..3 -> cols w*32..w*32+32
  const int l = tid & 63;
  const int lr = l & 15, lg = l >> 4;
  const int bb = blockIdx.x >> 6;
  const int row0 = (blockIdx.x & 63) * BM;

  // A staging: thread owns row ar, 16 consecutive ints at col base ac (per K-step)
  const int ar = tid >> 3;
  const int ac = (tid & 7) * 16;
  const size_t adj_row = ((size_t)(bb * Nn + row0 + ar)) * Nn + ac;

  f32x4 acc[2][2] = {};
  int dsum = 0;

  int4v a_reg[4];
  ushort8 b_reg[8];

  // prologue loads (kt = 0)
  #pragma unroll
  for (int c = 0; c < 4; ++c) a_reg[c] = *(const int4v*)(adj + adj_row + c * 4);
  #pragma unroll
  for (int c = 0; c < 8; ++c) {
    int ch = tid + c * 256, d = ch >> 4, off = (ch & 15) * 8;
    b_reg[c] = *(const ushort8*)(inT + ((size_t)(bb * Dn + d)) * Nn + off);
  }

  for (int kt = 0; kt < Nn / KB; ++kt) {
    if (kt) __syncthreads();               // prev MFMA done reading LDS
    // convert + write A tile (and accumulate degree)
    ushort8 aw[2];
    #pragma unroll
    for (int c = 0; c < 4; ++c)
      #pragma unroll
      for (int e = 0; e < 4; ++e) {
        int v = a_reg[c][e];
        dsum += (v != 0);
        int idx = c * 4 + e;
        aw[idx >> 3][idx & 7] = (v != 0) ? (unsigned short)0x3F80u : (unsigned short)0u;
      }
    *(ushort8*)&As[ar][ac] = aw[0];
    *(ushort8*)&As[ar][ac + 8] = aw[1];
    // write B tile
    #pragma unroll
    for (int c = 0; c < 8; ++c) {
      int ch = tid + c * 256, d = ch >> 4, off = (ch & 15) * 8;
      *(ushort8*)&Bs[d][off] = b_reg[c];
    }
    __syncthreads();
    // prefetch next tile into regs (overlaps with MFMA below)
    if (kt + 1 < Nn / KB) {
      const int k0n = (kt + 1) * KB;
      #pragma unroll
      for (int c = 0; c < 4; ++c) a_reg[c] = *(const int4v*)(adj + adj_row + k0n + c * 4);
      #pragma unroll
      for (int c = 0; c < 8; ++c) {
        int ch = tid + c * 256, d = ch >> 4, off = (ch & 15) * 8;
        b_reg[c] = *(const ushort8*)(inT + ((size_t)(bb * Dn + d)) * Nn + k0n + off);
      }
    }
    // MFMA over this K-tile
    #pragma unroll
    for (int kc = 0; kc < 4; ++kc) {
      bf16x8 af[2], bfm[2];
      #pragma unroll
      for (int mf = 0; mf < 2; ++mf)
        af[mf] = *(const bf16x8*)&As[mf * 16 + lr][kc * 32 + lg * 8];
      #pragma unroll
      for (int cf = 0; cf < 2; ++cf)
        bfm[cf] = *(const bf16x8*)&Bs[w * 32 + cf * 16 + lr][kc * 32 + lg * 8];
      #pragma unroll
      for (int mf = 0; mf < 2; ++mf)
        #pragma unroll
        for (int cf = 0; cf < 2; ++cf)
          acc[mf][cf] = __builtin_amdgcn_mfma_f32_16x16x32_bf16(af[mf], bfm[cf], acc[mf][cf], 0, 0, 0);
    }
  }

  // ---- degree: reduce across the 8 staging threads of each row ----
  {
    int s = dsum;
    s += __shfl_down(s, 1);
    s += __shfl_down(s, 2);
    s += __shfl_down(s, 4);
    if ((tid & 7) == 0) {
      float fd = (float)s;
      degs[tid >> 3] = (fd == 0.0f) ? 1.0f : fd;
    }
  }
  __syncthreads();

  // ---- stage feat = [x | agg] as bf16 in LDS ----
  #pragma unroll
  for (int c = 0; c < 2; ++c) {
    int ch = tid + c * 256, r = ch >> 4, off = (ch & 15) * 8;
    const float* src = input_ + ((size_t)(bb * Nn + row0 + r)) * Dn + off;
    float4v f0 = *(const float4v*)(src);
    float4v f1 = *(const float4v*)(src + 4);
    ushort8 v;
    #pragma unroll
    for (int e = 0; e < 4; ++e) { v[e] = f2bf(f0[e]); v[e + 4] = f2bf(f1[e]); }
    *(ushort8*)&feat[r][off] = v;
  }
  #pragma unroll
  for (int mf = 0; mf < 2; ++mf)
    #pragma unroll
    for (int reg = 0; reg < 4; ++reg) {
      int row = mf * 16 + lg * 4 + reg;
      float d = degs[row];
      #pragma unroll
      for (int cf = 0; cf < 2; ++cf) {
        int col = w * 32 + cf * 16 + lr;
        feat[row][Dn + col] = f2bf(acc[mf][cf][reg] / d);
      }
    }
  __syncthreads();

  // ---- second GEMM: out_pre = feat @ W  (K = 256), B-frags straight from L2-hot WT ----
  f32x4 acc2[2][2] = {};
  #pragma unroll
  for (int ks = 0; ks < 8; ++ks) {
    bf16x8 af[2], bw[2];
    #pragma unroll
    for (int mf = 0; mf < 2; ++mf)
      af[mf] = *(const bf16x8*)&feat[mf * 16 + lr][ks * 32 + lg * 8];
    #pragma unroll
    for (int cf = 0; cf < 2; ++cf)
      bw[cf] = *(const bf16x8*)(WT + (size_t)(w * 32 + cf * 16 + lr) * 256 + ks * 32 + lg * 8);
    #pragma unroll
    for (int mf = 0; mf < 2; ++mf)
      #pragma unroll
      for (int cf = 0; cf < 2; ++cf)
        acc2[mf][cf] = __builtin_amdgcn_mfma_f32_16x16x32_bf16(af[mf], bw[cf], acc2[mf][cf], 0, 0, 0);
  }

  // ---- bias + sigmoid + row L2-norm + store ----
  float bcol[2];
  bcol[0] = bvec[w * 32 + lr];
  bcol[1] = bvec[w * 32 + 16 + lr];
  float sg[2][2][4];
  #pragma unroll
  for (int mf = 0; mf < 2; ++mf)
    #pragma unroll
    for (int cf = 0; cf < 2; ++cf)
      #pragma unroll
      for (int reg = 0; reg < 4; ++reg) {
        float x = acc2[mf][cf][reg] + bcol[cf];
        sg[mf][cf][reg] = 1.0f / (1.0f + expf(-x));
      }
  #pragma unroll
  for (int mf = 0; mf < 2; ++mf)
    #pragma unroll
    for (int reg = 0; reg < 4; ++reg) {
      float p = sg[mf][0][reg] * sg[mf][0][reg] + sg[mf][1][reg] * sg[mf][1][reg];
      p += __shfl_xor(p, 1);
      p += __shfl_xor(p, 2);
      p += __shfl_xor(p, 4);
      p += __shfl_xor(p, 8);
      if (lr == 0) rowsum[mf * 16 + lg * 4 + reg][w] = p;
    }
  __syncthreads();
  #pragma unroll
  for (int mf = 0; mf < 2; ++mf)
    #pragma unroll
    for (int reg = 0; reg < 4; ++reg) {
      int row = mf * 16 + lg * 4 + reg;
      float inv = rsqrtf(rowsum[row][0] + rowsum[row][1] + rowsum[row][2] + rowsum[row][3]);
      #pragma unroll
      for (int cf = 0; cf < 2; ++cf)
        out[((size_t)(bb * Nn + row0 + row)) * OUTn + w * 32 + cf * 16 + lr] =
            sg[mf][cf][reg] * inv;
    }
}

extern "C" void kernel_launch(void* const* d_in, const int* in_sizes, int n_in,
                              void* d_out, int out_size, void* d_ws, size_t ws_size,
                              hipStream_t stream) {
  (void)in_sizes; (void)n_in; (void)out_size; (void)ws_size;
  const float* input_ = (const float*)d_in[0];
  const int* adj = (const int*)d_in[1];
  const float* W = (const float*)d_in[2];
  const float* bvec = (const float*)d_in[3];
  float* out = (float*)d_out;

  unsigned short* inT = (unsigned short*)d_ws;                 // 8*128*2048 bf16 = 4 MB
  unsigned short* WT = inT + (size_t)Bn * Dn * Nn;             // 128*256 bf16 = 64 KB

  hipLaunchKernelGGL(gcn_transpose_in, dim3(256), dim3(256), 0, stream, input_, inT);
  hipLaunchKernelGGL(gcn_prep_wt, dim3(128), dim3(256), 0, stream, W, WT);
  hipLaunchKernelGGL(gcn_main, dim3(512), dim3(256), 0, stream, input_, adj, bvec, inT, WT, out);
}